// Round 6
// baseline (41.945 us; speedup 1.0000x reference)
//
#include <hip/hip_runtime.h>
#include <hip/hip_fp16.h>

// out[m][n] = fp16( fp16( (sum_k x[m][k]*w6[n][k]) * scale[n] ) + bias[n] ), stored fp32
// All inputs pushed as fp32 (fp16-exact values): convert to fp16 (exact), f16 MFMA.
// Pipelined: BK=128, LDS double-buffer (1 barrier/phase), 2-tile reg prefetch queue.

typedef __attribute__((ext_vector_type(8))) _Float16 half8;
typedef __attribute__((ext_vector_type(2))) __fp16 fp16x2;  // cvt_pkrtz return type
typedef __attribute__((ext_vector_type(4))) float f32x4;

constexpr int K  = 4096;
constexpr int N  = 4096;
constexpr int BM = 64;
constexpr int BN = 64;
constexpr int BK = 128;
constexpr int NT = K / BK;          // 32 K-tiles
constexpr int LDH   = BK + 8;       // 136 halves = 272B row stride (rows spread 8 bank-groups)
constexpr int TILEH = 64 * LDH;     // halves per operand tile
// lds layout: [buf(2)][op(2: A=x, B=w)][64][LDH]

__device__ __forceinline__ void pack_store(_Float16* dst, float4 a, float4 b,
                                           float4 c, float4 d) {
    half8 h0, h1; fp16x2 p;
    p = __builtin_amdgcn_cvt_pkrtz(a.x, a.y); h0[0]=(_Float16)p[0]; h0[1]=(_Float16)p[1];
    p = __builtin_amdgcn_cvt_pkrtz(a.z, a.w); h0[2]=(_Float16)p[0]; h0[3]=(_Float16)p[1];
    p = __builtin_amdgcn_cvt_pkrtz(b.x, b.y); h0[4]=(_Float16)p[0]; h0[5]=(_Float16)p[1];
    p = __builtin_amdgcn_cvt_pkrtz(b.z, b.w); h0[6]=(_Float16)p[0]; h0[7]=(_Float16)p[1];
    p = __builtin_amdgcn_cvt_pkrtz(c.x, c.y); h1[0]=(_Float16)p[0]; h1[1]=(_Float16)p[1];
    p = __builtin_amdgcn_cvt_pkrtz(c.z, c.w); h1[2]=(_Float16)p[0]; h1[3]=(_Float16)p[1];
    p = __builtin_amdgcn_cvt_pkrtz(d.x, d.y); h1[4]=(_Float16)p[0]; h1[5]=(_Float16)p[1];
    p = __builtin_amdgcn_cvt_pkrtz(d.z, d.w); h1[6]=(_Float16)p[0]; h1[7]=(_Float16)p[1];
    *(half8*)(dst)     = h0;
    *(half8*)(dst + 8) = h1;
}

__global__ __launch_bounds__(512, 2)
void fp6lin_kernel(const float* __restrict__ X,
                   const float* __restrict__ W,
                   const float* __restrict__ S,
                   const float* __restrict__ Bi,
                   float* __restrict__ O)
{
    __shared__ __align__(16) _Float16 lds[4 * TILEH];   // 69,632 B

    const int tid  = (int)threadIdx.x;
    const int lane = tid & 63;
    const int wid  = tid >> 6;          // 8 waves: 2 (M) x 4 (N), wave tile 32x16
    const int wm   = (wid & 1) * 32;
    const int wn   = (wid >> 1) * 16;

    // XCD swizzle: the 4 M-tiles sharing a W panel land adjacent on one XCD.
    const int bid = (int)blockIdx.x;
    const int swz = (bid & 7) * 32 + (bid >> 3);
    const int bm  = (swz & 3) * BM;
    const int bn  = (swz >> 2) * BN;

    // staging: thread t -> row t>>3 (64 rows), 16 consecutive floats at col (t&7)*16
    const int srow = tid >> 3;
    const int scol = (tid & 7) * 16;
    const float* xp = X + (size_t)(bm + srow) * K + scol;
    const float* wp = W + (size_t)(bn + srow) * K + scol;
    _Float16* stA = lds + srow * LDH + scol;            // x tile (op 0)
    _Float16* stB = lds + TILEH + srow * LDH + scol;    // w tile (op 1)

    // frag read pointers (16x16x32 layout: row=lane&15, k=(lane>>4)*8+j)
    const _Float16* pa = lds + (wm + (lane & 15)) * LDH + ((lane >> 4) << 3);
    const _Float16* pb = lds + TILEH + (wn + (lane & 15)) * LDH + ((lane >> 4) << 3);

    // hoist epilogue scalars (consumed ~15us later; latency free)
    const int orow = bm + wm + ((lane >> 4) << 2);
    const int ocol = bn + wn + (lane & 15);
    const float sc = S[ocol];
    const float bi = Bi[ocol];

    f32x4 acc0 = {0.f, 0.f, 0.f, 0.f};
    f32x4 acc1 = {0.f, 0.f, 0.f, 0.f};

    // two named register tile-slots (no runtime indexing -> stays in VGPRs)
    float4 s0w0, s0w1, s0w2, s0w3, s0x0, s0x1, s0x2, s0x3;
    float4 s1w0, s1w1, s1w2, s1w3, s1x0, s1x1, s1x2, s1x3;

#define LOAD0(t) do { const float* q = wp + (t) * BK; const float* r = xp + (t) * BK; \
        s0w0 = *(const float4*)(q);      s0w1 = *(const float4*)(q + 4);             \
        s0w2 = *(const float4*)(q + 8);  s0w3 = *(const float4*)(q + 12);            \
        s0x0 = *(const float4*)(r);      s0x1 = *(const float4*)(r + 4);             \
        s0x2 = *(const float4*)(r + 8);  s0x3 = *(const float4*)(r + 12); } while (0)
#define LOAD1(t) do { const float* q = wp + (t) * BK; const float* r = xp + (t) * BK; \
        s1w0 = *(const float4*)(q);      s1w1 = *(const float4*)(q + 4);             \
        s1w2 = *(const float4*)(q + 8);  s1w3 = *(const float4*)(q + 12);            \
        s1x0 = *(const float4*)(r);      s1x1 = *(const float4*)(r + 4);             \
        s1x2 = *(const float4*)(r + 8);  s1x3 = *(const float4*)(r + 12); } while (0)
#define STORE0(buf) do { int o = (buf) * 2 * TILEH;                     \
        pack_store(stA + o, s0x0, s0x1, s0x2, s0x3);                    \
        pack_store(stB + o, s0w0, s0w1, s0w2, s0w3); } while (0)
#define STORE1(buf) do { int o = (buf) * 2 * TILEH;                     \
        pack_store(stA + o, s1x0, s1x1, s1x2, s1x3);                    \
        pack_store(stB + o, s1w0, s1w1, s1w2, s1w3); } while (0)
#define COMPUTE(buf) do { int o = (buf) * 2 * TILEH;                    \
        _Pragma("unroll")                                               \
        for (int kk = 0; kk < BK / 32; ++kk) {                          \
            half8 a0 = *(const half8*)(pa + o + kk * 32);               \
            half8 a1 = *(const half8*)(pa + o + 16 * LDH + kk * 32);    \
            half8 b  = *(const half8*)(pb + o + kk * 32);               \
            acc0 = __builtin_amdgcn_mfma_f32_16x16x32_f16(a0, b, acc0, 0, 0, 0); \
            acc1 = __builtin_amdgcn_mfma_f32_16x16x32_f16(a1, b, acc1, 0, 0, 0); \
        } } while (0)

    // prologue: slot0 <- tile0, slot1 <- tile1, stage tile0 into buf0
    LOAD0(0);
    LOAD1(1);
    STORE0(0);
    __syncthreads();

    // steady state invariant at even phase t: buf0 = tile t (ready), slot1 = tile t+1
    for (int t2 = 0; t2 < NT; t2 += 2) {
        // even phase: compute buf0, stage slot1 -> buf1, prefetch tile t2+2 -> slot0
        if (t2 + 2 < NT) LOAD0(t2 + 2);
        COMPUTE(0);
        STORE1(1);                  // cvt waits on slot1 loads issued ~2 phases ago
        __syncthreads();
        // odd phase: compute buf1, stage slot0 -> buf0, prefetch tile t2+3 -> slot1
        if (t2 + 3 < NT) LOAD1(t2 + 3);
        COMPUTE(1);
        if (t2 + 2 < NT) STORE0(0);
        __syncthreads();
    }
#undef LOAD0
#undef LOAD1
#undef STORE0
#undef STORE1
#undef COMPUTE

    // epilogue: C/D layout col=lane&15, row=(lane>>4)*4+reg [m89/m91]
    // reference rounding: fp16(acc*scale) then fp16(+bias), stored fp32
    #pragma unroll
    for (int r = 0; r < 4; ++r) {
        _Float16 h0 = (_Float16)(acc0[r] * sc);
        _Float16 h1 = (_Float16)((float)h0 + bi);
        O[(size_t)(orow + r) * N + ocol] = (float)h1;
        _Float16 g0 = (_Float16)(acc1[r] * sc);
        _Float16 g1 = (_Float16)((float)g0 + bi);
        O[(size_t)(orow + 16 + r) * N + ocol] = (float)g1;
    }
}

extern "C" void kernel_launch(void* const* d_in, const int* in_sizes, int n_in,
                              void* d_out, int out_size, void* d_ws, size_t ws_size,
                              hipStream_t stream) {
    const float* x  = (const float*)d_in[0];
    const float* w  = (const float*)d_in[1];
    const float* s  = (const float*)d_in[2];
    const float* bi = (const float*)d_in[3];
    float* o = (float*)d_out;

    fp6lin_kernel<<<dim3(256), dim3(512), 0, stream>>>(x, w, s, bi, o);
}